// Round 3
// baseline (160.188 us; speedup 1.0000x reference)
//
#include <hip/hip_runtime.h>

// MedSegNet texture features: 3x3 zero-padded window per (b,c,h,w):
//  contrast, energy, entropy, homogeneity -> martingale transform.
// theta=1 => M = clamp(max(f,1e-5)*exp(-0.5), 1e-4, 1e4); all feats <= 1 so
// the EXP_MAX clamp / isfinite path is dead code.
//
// R3 = R2 with the nontemporal stores using a native clang vector type
// (ext_vector_type) — __builtin_nontemporal_store rejects HIP_vector_type.

#define Wd 128
#define Hd 128
#define HWd 16384

typedef float v4f __attribute__((ext_vector_type(4)));

__device__ __forceinline__ float mart(float f) {
    float fc = fmaxf(f, 1e-5f);
    float M = fc * 0.60653065971263342f;   // exp(-0.5)
    return fminf(fmaxf(M, 1e-4f), 1e4f);
}

__global__ __launch_bounds__(256) void medseg_kernel(const float* __restrict__ x,
                                                     float* __restrict__ out) {
    int tid = blockIdx.x * 256 + threadIdx.x;
    int plane = tid >> 12;                // 4096 threads per 128x128 plane
    int rem = tid & 4095;
    int h = rem >> 5;                     // 32 groups-of-4 per row
    int lane31 = rem & 31;
    int w0 = lane31 << 2;

    const float* xp = x + (size_t)plane * HWd;

    // 3 rows x 4 center cols (w0..w0+3), zero-padded rows
    v4f v[3];
#pragma unroll
    for (int dr = 0; dr < 3; ++dr) {
        int hh = h + dr - 1;
        if (hh < 0 || hh >= Hd) {
            v[dr] = (v4f){0.f, 0.f, 0.f, 0.f};
        } else {
            v[dr] = *reinterpret_cast<const v4f*>(xp + hh * Wd + w0);
        }
    }

    // halo columns from neighbor lanes (convergent code). Lane layout: 32
    // consecutive lanes cover one row; lane31==0 is the left image edge.
    float r[3][6];
#pragma unroll
    for (int dr = 0; dr < 3; ++dr) {
        float left  = __shfl_up(v[dr].w, 1);
        float right = __shfl_down(v[dr].x, 1);
        r[dr][0] = (lane31 == 0)  ? 0.f : left;
        r[dr][1] = v[dr].x; r[dr][2] = v[dr].y; r[dr][3] = v[dr].z; r[dr][4] = v[dr].w;
        r[dr][5] = (lane31 == 31) ? 0.f : right;
    }

    // column partial sums shared across the 4 output pixels
    float colS[6], colE[6], colN[6];
#pragma unroll
    for (int j = 0; j < 6; ++j) {
        float s = 0.f, e = 0.f, en = 0.f;
#pragma unroll
        for (int dr = 0; dr < 3; ++dr) {
            float vv = r[dr][j];
            s += vv;
            e = fmaf(vv, vv, e);
            float cl = fmaxf(vv, 1e-6f);
            en = fmaf(cl, __logf(cl), en);
        }
        colS[j] = s; colE[j] = e; colN[j] = en;
    }

    float con[4], ene[4], ent[4], hom[4];
#pragma unroll
    for (int i = 0; i < 4; ++i) {
        float sum = colS[i] + colS[i + 1] + colS[i + 2];
        float m = sum * (1.f / 9.f);
        float energy = (colE[i] + colE[i + 1] + colE[i + 2]) * (1.f / 9.f);
        float entropy = -(colN[i] + colN[i + 1] + colN[i + 2]) * (1.f / 9.f);

        float s2 = 0.f, sa = 0.f;
#pragma unroll
        for (int dr = 0; dr < 3; ++dr) {
#pragma unroll
            for (int dj = 0; dj < 3; ++dj) {
                float c = r[dr][i + dj] - m;
                s2 = fmaf(c, c, s2);
                sa += fabsf(c);
            }
        }
        float var = s2 * 0.125f;                      // ddof=1 -> /8
        float sd = fmaxf(sqrtf(var), 1e-3f);
        float contrast = s2 * (1.f / 9.f) / (sd * sd);
        float homog = 1.f / ((9.f + sa) * (1.f / 9.f) + 1e-6f);

        con[i] = mart(contrast);
        ene[i] = mart(energy);
        ent[i] = mart(entropy);
        hom[i] = mart(homog);
    }

    size_t base = (size_t)plane * 4 * HWd + h * Wd + w0;
    __builtin_nontemporal_store((v4f){con[0], con[1], con[2], con[3]},
                                reinterpret_cast<v4f*>(out + base));
    __builtin_nontemporal_store((v4f){ene[0], ene[1], ene[2], ene[3]},
                                reinterpret_cast<v4f*>(out + base + HWd));
    __builtin_nontemporal_store((v4f){ent[0], ent[1], ent[2], ent[3]},
                                reinterpret_cast<v4f*>(out + base + 2 * HWd));
    __builtin_nontemporal_store((v4f){hom[0], hom[1], hom[2], hom[3]},
                                reinterpret_cast<v4f*>(out + base + 3 * HWd));
}

extern "C" void kernel_launch(void* const* d_in, const int* in_sizes, int n_in,
                              void* d_out, int out_size, void* d_ws, size_t ws_size,
                              hipStream_t stream) {
    const float* x = (const float*)d_in[0];
    float* out = (float*)d_out;
    int n_planes = in_sizes[0] / HWd;            // B*C = 512
    int total_threads = n_planes * (HWd / 4);
    int blocks = total_threads / 256;            // exact: 8192
    medseg_kernel<<<blocks, 256, 0, stream>>>(x, out);
}